// Round 2
// baseline (558.884 us; speedup 1.0000x reference)
//
#include <hip/hip_runtime.h>
#include <hip/hip_cooperative_groups.h>
#include <cmath>

namespace cg = cooperative_groups;

#define BATCH 128
#define KDIM 1024
#define VOCAB 32001
#define G3 3072
#define GIP_STRIDE (BATCH * G3)   // floats per split-K partial
#define NEGF (-3.0e38f)

typedef __bf16 bf16_t;
typedef bf16_t bf16x8 __attribute__((ext_vector_type(8)));
typedef float f32x4 __attribute__((ext_vector_type(4)));

// ---------------- async global->LDS (16B/lane, lanes contiguous per wave) ----
__device__ __forceinline__ void stage16(const void* g, void* lds) {
    __builtin_amdgcn_global_load_lds(
        (const __attribute__((address_space(1))) void*)g,
        (__attribute__((address_space(3))) void*)lds, 16, 0, 0);
}

// ---------------- GEMM core ---------------------------------------------------
// C[0:128, n0:n0+64] = A_bf16[128,1024] * W_f32[Wrows,1024]^T (+bias)
// BK=64/stage, double-buffered LDS (2-phase pipeline), 256 thr = 4 waves.
// sA: bf16 [128][64], row=128B=8 granules, phys granule = g ^ (row&7)
// sB: f32  [64][64],  row=256B=16 granules, phys granule = g ^ (row&15)
template<bool BIAS>
__device__ __forceinline__ void gemm_core(
    const bf16_t* __restrict__ A, const float* __restrict__ W,
    const float* __restrict__ bias, float* __restrict__ C,
    int ldc, int Wrows, int n0, int kbeg, int kend)
{
    __shared__ bf16_t sA[2][128 * 64];   // 2 x 16 KB
    __shared__ float  sB[2][64 * 64];    // 2 x 16 KB
    const int t    = threadIdx.x;
    const int wave = t >> 6;
    const int lane = t & 63;
    const int l15  = lane & 15;
    const int quad = lane >> 4;
    const int wm   = wave & 1;
    const int wn   = wave >> 1;

    const bf16_t* aSrc[4]; int aDst[4];
#pragma unroll
    for (int r = 0; r < 4; ++r) {
        const int row = r * 32 + (t >> 3);
        const int sg  = t & 7;
        const int kg  = sg ^ (row & 7);
        aSrc[r] = A + (size_t)row * KDIM + kg * 8 + kbeg;
        aDst[r] = row * 128 + sg * 16;
    }
    const float* wSrc[4]; int wDst[4];
#pragma unroll
    for (int r = 0; r < 4; ++r) {
        const int row = r * 16 + (t >> 4);
        int wr = n0 + row; if (wr > Wrows - 1) wr = Wrows - 1;
        const int sg = t & 15;
        const int kg = sg ^ (row & 15);
        wSrc[r] = W + (size_t)wr * KDIM + kg * 4 + kbeg;
        wDst[r] = row * 256 + sg * 16;
    }

    f32x4 acc[4][2];
#pragma unroll
    for (int i = 0; i < 4; ++i)
#pragma unroll
        for (int j = 0; j < 2; ++j) acc[i][j] = f32x4{0.f, 0.f, 0.f, 0.f};

    const int nstages = (kend - kbeg) >> 6;
#pragma unroll
    for (int r = 0; r < 4; ++r) stage16(aSrc[r], (char*)sA[0] + aDst[r]);
#pragma unroll
    for (int r = 0; r < 4; ++r) stage16(wSrc[r], (char*)sB[0] + wDst[r]);
    __syncthreads();

    int cur = 0;
    for (int st = 0; st < nstages; ++st) {
        if (st + 1 < nstages) {
            const int off = (st + 1) << 6;
#pragma unroll
            for (int r = 0; r < 4; ++r) stage16(aSrc[r] + off, (char*)sA[cur ^ 1] + aDst[r]);
#pragma unroll
            for (int r = 0; r < 4; ++r) stage16(wSrc[r] + off, (char*)sB[cur ^ 1] + wDst[r]);
        }
        const char* sAc = (const char*)sA[cur];
        const char* sBc = (const char*)sB[cur];
#pragma unroll
        for (int s = 0; s < 2; ++s) {
            bf16x8 bfr[2];
#pragma unroll
            for (int j = 0; j < 2; ++j) {
                const int row = wn * 32 + j * 16 + l15;
                const int gu  = (s * 8 + 2 * quad) ^ (row & 15);
                const f32x4 u = *(const f32x4*)(sBc + row * 256 + gu * 16);
                const f32x4 v = *(const f32x4*)(sBc + row * 256 + (gu ^ 1) * 16);
                bf16x8 b;
                b[0] = (bf16_t)u[0]; b[1] = (bf16_t)u[1]; b[2] = (bf16_t)u[2]; b[3] = (bf16_t)u[3];
                b[4] = (bf16_t)v[0]; b[5] = (bf16_t)v[1]; b[6] = (bf16_t)v[2]; b[7] = (bf16_t)v[3];
                bfr[j] = b;
            }
#pragma unroll
            for (int i = 0; i < 4; ++i) {
                const int row  = wm * 64 + i * 16 + l15;
                const int phys = (s * 4 + quad) ^ (row & 7);
                const bf16x8 af = *(const bf16x8*)(sAc + row * 128 + phys * 16);
#pragma unroll
                for (int j = 0; j < 2; ++j)
                    acc[i][j] = __builtin_amdgcn_mfma_f32_16x16x32_bf16(
                        af, bfr[j], acc[i][j], 0, 0, 0);
            }
        }
        __syncthreads();
        cur ^= 1;
    }

#pragma unroll
    for (int j = 0; j < 2; ++j) {
        const int col = n0 + wn * 32 + j * 16 + l15;
        if (col < Wrows) {
            const float bv = BIAS ? bias[col] : 0.f;
#pragma unroll
            for (int i = 0; i < 4; ++i)
#pragma unroll
                for (int r = 0; r < 4; ++r) {
                    const int row = wm * 64 + i * 16 + quad * 4 + r;
                    C[(size_t)row * ldc + col] = acc[i][j][r] + bv;
                }
        }
    }
}

// ---- launch 1: three independent GEMMs (gi0, gh0, gh1), split-K=4 ----------
// A buffers xb|hp0b|hp1b are contiguous; partials P + z*4*GIP_STRIDE
__global__ __launch_bounds__(256, 2) void gemm_gru3(
    const bf16_t* __restrict__ Abase, const float* __restrict__ w0,
    const float* __restrict__ w1, const float* __restrict__ w2,
    float* __restrict__ Pbase)
{
    const int split = blockIdx.x;
    const int n0    = blockIdx.y * 64;
    const int z     = blockIdx.z;
    const float* W  = (z == 0) ? w0 : ((z == 1) ? w1 : w2);
    gemm_core<false>(Abase + (size_t)z * BATCH * KDIM, W, nullptr,
                     Pbase + (size_t)z * 4 * GIP_STRIDE + (size_t)split * GIP_STRIDE,
                     G3, G3, n0, split * 256, split * 256 + 256);
}

// ---- launch 2: gi1 only (depends on h0) ------------------------------------
__global__ __launch_bounds__(256, 2) void gemm_gru1(
    const bf16_t* __restrict__ A, const float* __restrict__ W,
    float* __restrict__ P)
{
    const int split = blockIdx.x;
    const int n0    = blockIdx.y * 64;
    gemm_core<false>(A, W, nullptr, P + (size_t)split * GIP_STRIDE,
                     G3, G3, n0, split * 256, split * 256 + 256);
}

// ---- fused vocab GEMM + log-softmax (cooperative, 501 blocks) --------------
__global__ __launch_bounds__(256, 2) void vocab_fused(
    const bf16_t* __restrict__ A, const float* __restrict__ W,
    const float* __restrict__ bias, float* __restrict__ C,
    float* __restrict__ pm, float* __restrict__ ps, float* __restrict__ Lrow)
{
    __shared__ bf16_t sA[2][128 * 64];
    __shared__ float  sB[2][64 * 64];
    __shared__ float  sPm[2][128], sPs[2][128];
    __shared__ float  sL[128];
    __shared__ float  swm[4], sws[4];

    const int bid  = blockIdx.x;
    const int n0   = bid * 64;
    const int t    = threadIdx.x;
    const int wave = t >> 6;
    const int lane = t & 63;
    const int l15  = lane & 15;
    const int quad = lane >> 4;
    const int wm   = wave & 1;
    const int wn   = wave >> 1;

    const bf16_t* aSrc[4]; int aDst[4];
#pragma unroll
    for (int r = 0; r < 4; ++r) {
        const int row = r * 32 + (t >> 3);
        const int sg  = t & 7;
        const int kg  = sg ^ (row & 7);
        aSrc[r] = A + (size_t)row * KDIM + kg * 8;
        aDst[r] = row * 128 + sg * 16;
    }
    const float* wSrc[4]; int wDst[4];
#pragma unroll
    for (int r = 0; r < 4; ++r) {
        const int row = r * 16 + (t >> 4);
        int wr = n0 + row; if (wr > VOCAB - 1) wr = VOCAB - 1;
        const int sg = t & 15;
        const int kg = sg ^ (row & 15);
        wSrc[r] = W + (size_t)wr * KDIM + kg * 4;
        wDst[r] = row * 256 + sg * 16;
    }

    f32x4 acc[4][2];
#pragma unroll
    for (int i = 0; i < 4; ++i)
#pragma unroll
        for (int j = 0; j < 2; ++j) acc[i][j] = f32x4{0.f, 0.f, 0.f, 0.f};

#pragma unroll
    for (int r = 0; r < 4; ++r) stage16(aSrc[r], (char*)sA[0] + aDst[r]);
#pragma unroll
    for (int r = 0; r < 4; ++r) stage16(wSrc[r], (char*)sB[0] + wDst[r]);
    __syncthreads();

    int cur = 0;
    for (int st = 0; st < 16; ++st) {
        if (st + 1 < 16) {
            const int off = (st + 1) << 6;
#pragma unroll
            for (int r = 0; r < 4; ++r) stage16(aSrc[r] + off, (char*)sA[cur ^ 1] + aDst[r]);
#pragma unroll
            for (int r = 0; r < 4; ++r) stage16(wSrc[r] + off, (char*)sB[cur ^ 1] + wDst[r]);
        }
        const char* sAc = (const char*)sA[cur];
        const char* sBc = (const char*)sB[cur];
#pragma unroll
        for (int s = 0; s < 2; ++s) {
            bf16x8 bfr[2];
#pragma unroll
            for (int j = 0; j < 2; ++j) {
                const int row = wn * 32 + j * 16 + l15;
                const int gu  = (s * 8 + 2 * quad) ^ (row & 15);
                const f32x4 u = *(const f32x4*)(sBc + row * 256 + gu * 16);
                const f32x4 v = *(const f32x4*)(sBc + row * 256 + (gu ^ 1) * 16);
                bf16x8 b;
                b[0] = (bf16_t)u[0]; b[1] = (bf16_t)u[1]; b[2] = (bf16_t)u[2]; b[3] = (bf16_t)u[3];
                b[4] = (bf16_t)v[0]; b[5] = (bf16_t)v[1]; b[6] = (bf16_t)v[2]; b[7] = (bf16_t)v[3];
                bfr[j] = b;
            }
#pragma unroll
            for (int i = 0; i < 4; ++i) {
                const int row  = wm * 64 + i * 16 + l15;
                const int phys = (s * 4 + quad) ^ (row & 7);
                const bf16x8 af = *(const bf16x8*)(sAc + row * 128 + phys * 16);
#pragma unroll
                for (int j = 0; j < 2; ++j)
                    acc[i][j] = __builtin_amdgcn_mfma_f32_16x16x32_bf16(
                        af, bfr[j], acc[i][j], 0, 0, 0);
            }
        }
        __syncthreads();
        cur ^= 1;
    }

    // ---- epilogue phase 1: add bias, per-block row partials (m, s) ---------
#pragma unroll
    for (int j = 0; j < 2; ++j) {
        int col = n0 + wn * 32 + j * 16 + l15;
        const float bv = bias[col < VOCAB ? col : VOCAB - 1];
#pragma unroll
        for (int i = 0; i < 4; ++i)
#pragma unroll
            for (int r = 0; r < 4; ++r) acc[i][j][r] += bv;
    }
    {
        const int col0 = n0 + wn * 32 + l15;
        const bool ok0 = col0 < VOCAB, ok1 = (col0 + 16) < VOCAB;
        float rm[4][4], rs[4][4];
#pragma unroll
        for (int i = 0; i < 4; ++i)
#pragma unroll
            for (int r = 0; r < 4; ++r) {
                const float v0 = acc[i][0][r], v1 = acc[i][1][r];
                float m = fmaxf(ok0 ? v0 : NEGF, ok1 ? v1 : NEGF);
                float s = (ok0 ? __expf(v0 - m) : 0.f) + (ok1 ? __expf(v1 - m) : 0.f);
#pragma unroll
                for (int msk = 1; msk < 16; msk <<= 1) {
                    const float mo = __shfl_xor(m, msk);
                    const float so = __shfl_xor(s, msk);
                    const float mn = fmaxf(m, mo);
                    s = s * __expf(m - mn) + so * __expf(mo - mn);
                    m = mn;
                }
                rm[i][r] = m; rs[i][r] = s;
            }
        if (l15 == 0) {
#pragma unroll
            for (int i = 0; i < 4; ++i)
#pragma unroll
                for (int r = 0; r < 4; ++r) {
                    const int row = wm * 64 + i * 16 + quad * 4 + r;
                    sPm[wn][row] = rm[i][r]; sPs[wn][row] = rs[i][r];
                }
        }
    }
    __syncthreads();
    if (t < 128) {
        const float m0 = sPm[0][t], s0 = sPs[0][t];
        const float m1 = sPm[1][t], s1 = sPs[1][t];
        const float mn = fmaxf(m0, m1);
        const float ss = s0 * __expf(m0 - mn) + s1 * __expf(m1 - mn);
        pm[(size_t)bid * 128 + t] = mn;
        ps[(size_t)bid * 128 + t] = ss;
    }
    __threadfence();
    cg::this_grid().sync();

    // ---- phase 2a: blocks 0..127 reduce 501 partials -> L[row] -------------
    if (bid < 128) {
        const int row = bid;
        float m = NEGF, s = 0.f;
        for (int i = t; i < 501; i += 256) {
            const float mo = pm[(size_t)i * 128 + row];
            const float so = ps[(size_t)i * 128 + row];
            const float mn = fmaxf(m, mo);
            s = s * __expf(m - mn) + so * __expf(mo - mn);
            m = mn;
        }
#pragma unroll
        for (int o = 32; o; o >>= 1) {
            const float mo = __shfl_down(m, o);
            const float so = __shfl_down(s, o);
            const float mn = fmaxf(m, mo);
            s = s * __expf(m - mn) + so * __expf(mo - mn);
            m = mn;
        }
        if ((t & 63) == 0) { swm[t >> 6] = m; sws[t >> 6] = s; }
        __syncthreads();
        if (t == 0) {
            float M = swm[0], S = sws[0];
#pragma unroll
            for (int w = 1; w < 4; ++w) {
                const float mn = fmaxf(M, swm[w]);
                S = S * __expf(M - mn) + sws[w] * __expf(swm[w] - mn);
                M = mn;
            }
            Lrow[row] = M + __logf(S);
        }
    }
    __threadfence();
    cg::this_grid().sync();

    // ---- phase 2b: write C = v - L[row] ------------------------------------
    if (t < 128) sL[t] = Lrow[t];
    __syncthreads();
#pragma unroll
    for (int j = 0; j < 2; ++j) {
        const int col = n0 + wn * 32 + j * 16 + l15;
        if (col < VOCAB) {
#pragma unroll
            for (int i = 0; i < 4; ++i)
#pragma unroll
                for (int r = 0; r < 4; ++r) {
                    const int row = wm * 64 + i * 16 + quad * 4 + r;
                    C[(size_t)row * VOCAB + col] = acc[i][j][r] - sL[row];
                }
        }
    }
}

// ---------------- prep: x=relu(emb[idx]) -> bf16; hidden[0/1] -> bf16 --------
__global__ __launch_bounds__(256) void prep_bf16(const int* __restrict__ idx,
                                                 const float* __restrict__ emb,
                                                 const float* __restrict__ hidden,
                                                 bf16_t* __restrict__ dst) {
    const int i = blockIdx.x * 256 + threadIdx.x;   // 0..98303 (x4 floats)
    const int sec = i >> 15;                        // 0:x 1:hp0 2:hp1
    const int j   = i & 32767;
    f32x4 v;
    if (sec == 0) {
        const int b = j >> 8, e4 = j & 255;
        v = ((const f32x4*)(emb + (size_t)idx[b] * KDIM))[e4];
#pragma unroll
        for (int k = 0; k < 4; ++k) v[k] = fmaxf(v[k], 0.f);
    } else {
        v = ((const f32x4*)(hidden + (size_t)(sec - 1) * (BATCH * KDIM)))[j];
    }
    bf16_t o[4];
#pragma unroll
    for (int k = 0; k < 4; ++k) o[k] = (bf16_t)v[k];
    *(uint64_t*)(dst + (size_t)i * 4) = *(const uint64_t*)o;
}

// ---------------- gate: sum 4 split-K partials + biases + GRU math -----------
__device__ __forceinline__ f32x4 sum_splits(const float* p) {
    f32x4 s = *(const f32x4*)p;
    s += *(const f32x4*)(p + GIP_STRIDE);
    s += *(const f32x4*)(p + 2 * GIP_STRIDE);
    s += *(const f32x4*)(p + 3 * GIP_STRIDE);
    return s;
}

__global__ __launch_bounds__(128) void gru_gate(const float* __restrict__ giP,
                                                const float* __restrict__ ghP,
                                                const float* __restrict__ b_ih,
                                                const float* __restrict__ b_hh,
                                                const float* __restrict__ hprev,
                                                float* __restrict__ hout,
                                                bf16_t* __restrict__ hout_bf16) {
    const int i  = blockIdx.x * 128 + threadIdx.x;  // 0..32767
    const int b  = i >> 8;
    const int j  = (i & 255) * 4;
    const size_t base = (size_t)b * G3 + j;

    f32x4 ir = sum_splits(giP + base),        hr = sum_splits(ghP + base);
    f32x4 iz = sum_splits(giP + base + 1024), hz = sum_splits(ghP + base + 1024);
    f32x4 in = sum_splits(giP + base + 2048), hn = sum_splits(ghP + base + 2048);
    const f32x4 bir = *(const f32x4*)(b_ih + j);
    const f32x4 biz = *(const f32x4*)(b_ih + j + 1024);
    const f32x4 bin = *(const f32x4*)(b_ih + j + 2048);
    const f32x4 bhr = *(const f32x4*)(b_hh + j);
    const f32x4 bhz = *(const f32x4*)(b_hh + j + 1024);
    const f32x4 bhn = *(const f32x4*)(b_hh + j + 2048);
    const f32x4 hp  = *(const f32x4*)(hprev + (size_t)b * KDIM + j);

    f32x4 o;
    bf16_t ob[4];
#pragma unroll
    for (int k = 0; k < 4; ++k) {
        const float r = 1.f / (1.f + __expf(-(ir[k] + bir[k] + hr[k] + bhr[k])));
        const float z = 1.f / (1.f + __expf(-(iz[k] + biz[k] + hz[k] + bhz[k])));
        const float a = in[k] + bin[k] + r * (hn[k] + bhn[k]);
        const float n = 1.f - 2.f / (__expf(2.f * a) + 1.f);   // tanh
        o[k] = (1.f - z) * n + z * hp[k];
        ob[k] = (bf16_t)o[k];
    }
    *(f32x4*)(hout + (size_t)b * KDIM + j) = o;
    *(uint64_t*)(hout_bf16 + (size_t)b * KDIM + j) = *(const uint64_t*)ob;
}

// ---------------- launch -----------------------------------------------------
extern "C" void kernel_launch(void* const* d_in, const int* in_sizes, int n_in,
                              void* d_out, int out_size, void* d_ws, size_t ws_size,
                              hipStream_t stream) {
    const int*   ivec  = (const int*)  d_in[0];
    const float* hidden= (const float*)d_in[1];
    const float* emb   = (const float*)d_in[2];
    const float* w_ih0 = (const float*)d_in[3];
    const float* w_hh0 = (const float*)d_in[4];
    const float* b_ih0 = (const float*)d_in[5];
    const float* b_hh0 = (const float*)d_in[6];
    const float* w_ih1 = (const float*)d_in[7];
    const float* w_hh1 = (const float*)d_in[8];
    const float* b_ih1 = (const float*)d_in[9];
    const float* b_hh1 = (const float*)d_in[10];
    const float* w_out = (const float*)d_in[11];
    const float* b_out = (const float*)d_in[12];

    float* out = (float*)d_out;
    float* h0  = out + (size_t)BATCH * VOCAB;   // hidden_out[0] (fp32)
    float* h1  = h0 + BATCH * KDIM;             // hidden_out[1] (fp32)

    // workspace layout (floats)
    float*  ws  = (float*)d_ws;
    float*  P   = ws;                                    // 12 * GIP_STRIDE (3 gemm partial-sets)
    bf16_t* xb  = (bf16_t*)(ws + 12 * (size_t)GIP_STRIDE);
    bf16_t* hp0b= xb   + BATCH * KDIM;
    bf16_t* hp1b= hp0b + BATCH * KDIM;
    bf16_t* h0b = hp1b + BATCH * KDIM;
    bf16_t* h1b = h0b  + BATCH * KDIM;
    float*  pm  = ws + 12 * (size_t)GIP_STRIDE + 5 * BATCH * KDIM / 2; // 5 bf16 bufs = 2.5 float-units each
    float*  ps_ = pm  + 501 * 128;
    float*  Lr  = ps_ + 501 * 128;

    (void)hp0b; (void)hp1b;

    prep_bf16<<<384, 256, 0, stream>>>(ivec, emb, hidden, xb);

    // launch 1: gi0, gh0, gh1 (gh1 depends only on inputs — hoisted off critical path)
    gemm_gru3<<<dim3(4, 48, 3), 256, 0, stream>>>(xb, w_ih0, w_hh0, w_hh1, P);
    gru_gate<<<256, 128, 0, stream>>>(P, P + 4 * (size_t)GIP_STRIDE,
                                      b_ih0, b_hh0, hidden, h0, h0b);

    // launch 2: gi1 only
    gemm_gru1<<<dim3(4, 48), 256, 0, stream>>>(h0b, w_ih1, P);
    gru_gate<<<256, 128, 0, stream>>>(P, P + 8 * (size_t)GIP_STRIDE,
                                      b_ih1, b_hh1, hidden + BATCH * KDIM, h1, h1b);

    // fused vocab GEMM + log-softmax (cooperative: 501 blocks, 2/CU co-resident)
    {
        const bf16_t* A_ = h1b; const float* W_ = w_out; const float* b_ = b_out;
        float* C_ = out; float* pm_ = pm; float* ps2_ = ps_; float* L_ = Lr;
        void* kargs[] = {&A_, &W_, &b_, &C_, &pm_, &ps2_, &L_};
        hipLaunchCooperativeKernel((const void*)vocab_fused, dim3(501), dim3(256),
                                   kargs, 0, stream);
    }
}